// Round 5
// baseline (997.954 us; speedup 1.0000x reference)
//
#include <hip/hip_runtime.h>
#include <math.h>

#define LPOS 4096   // H*W
#define NB 16       // batch

typedef __bf16 bf16;
typedef __bf16 bf16x8 __attribute__((ext_vector_type(8)));
typedef float f32x4 __attribute__((ext_vector_type(4)));

#define GLOAD_LDS16(g, l) \
    __builtin_amdgcn_global_load_lds((const __attribute__((address_space(1))) unsigned int*)(g), \
                                     (__attribute__((address_space(3))) unsigned int*)(l), 16, 0, 0)

__device__ __forceinline__ float sigm(float x){ return 1.f/(1.f+expf(-x)); }

// ---------------- depthwise 3x3 conv (pad 1), one (b,c) 64x64 plane per block ----------------
template<typename Tin, typename Tout>
__global__ void dwconv3x3_t(const Tin* __restrict__ in, const float* __restrict__ w9,
                            const float* __restrict__ bias, Tout* __restrict__ out, int C)
{
    int bc = blockIdx.x;
    int c = bc % C;
    __shared__ float tile[66][66];
    const Tin* p = in + (size_t)bc * LPOS;
    int tid = threadIdx.x;
    for (int i = tid; i < 66*66; i += 256) {
        int ty = i / 66, tx = i % 66;
        int y = ty - 1, x = tx - 1;
        float v = 0.f;
        if ((unsigned)y < 64u && (unsigned)x < 64u) v = (float)p[y*64 + x];
        tile[ty][tx] = v;
    }
    __syncthreads();
    float w[9];
#pragma unroll
    for (int i = 0; i < 9; i++) w[i] = w9[c*9 + i];
    float bb = bias ? bias[c] : 0.f;
    Tout* q = out + (size_t)bc * LPOS;
#pragma unroll
    for (int k = 0; k < 16; k++) {
        int px = tid + k*256;
        int y = px >> 6, x = px & 63;
        float s = bb;
#pragma unroll
        for (int dy = 0; dy < 3; dy++)
#pragma unroll
            for (int dx = 0; dx < 3; dx++)
                s += w[dy*3+dx] * tile[y+dy][x+dx];
        q[px] = (Tout)s;
    }
}

// ---- fused: x1 = (1-g)x + g*LN_dw1(conv);  xn = LN(x1) -> bf16 (C-major + pos-major) ----
__global__ __launch_bounds__(512)
void ln_x1xn_k(const bf16* __restrict__ conv, const float* __restrict__ xin,
               bf16* __restrict__ x1, bf16* __restrict__ xnC, bf16* __restrict__ xnT,
               const float* __restrict__ dww, const float* __restrict__ dwb,
               const float* __restrict__ g0,
               const float* __restrict__ lnw, const float* __restrict__ lnb)
{
    int b = blockIdx.x >> 6;
    int p = ((blockIdx.x & 63) << 6) + threadIdx.x;
    int ty = threadIdx.y;   // 0..7
    __shared__ float rs[8][64], rs2[8][64];
    float vals[32];
    float s = 0.f, s2 = 0.f;
    size_t bi = ((size_t)b*256 + ty*32)*LPOS + p;
#pragma unroll
    for (int i = 0; i < 32; i++) {
        float v = (float)conv[bi + (size_t)i*LPOS];
        vals[i] = v; s += v; s2 += v*v;
    }
    rs[ty][threadIdx.x] = s; rs2[ty][threadIdx.x] = s2;
    __syncthreads();
    float S = 0.f, S2 = 0.f;
#pragma unroll
    for (int j = 0; j < 8; j++) { S += rs[j][threadIdx.x]; S2 += rs2[j][threadIdx.x]; }
    float u = S*(1.f/256.f);
    float inv = rsqrtf(S2*(1.f/256.f) - u*u + 1e-5f);
    __syncthreads();
    s = 0.f; s2 = 0.f;
#pragma unroll
    for (int i = 0; i < 32; i++) {
        int c = ty*32 + i;
        float ln = dww[c]*((vals[i]-u)*inv) + dwb[c];
        float g  = sigm(g0[c]);
        float x1v = (1.f-g)*xin[bi + (size_t)i*LPOS] + g*ln;
        vals[i] = x1v;
        x1[bi + (size_t)i*LPOS] = (bf16)x1v;
        s += x1v; s2 += x1v*x1v;
    }
    rs[ty][threadIdx.x] = s; rs2[ty][threadIdx.x] = s2;
    __syncthreads();
    S = 0.f; S2 = 0.f;
#pragma unroll
    for (int j = 0; j < 8; j++) { S += rs[j][threadIdx.x]; S2 += rs2[j][threadIdx.x]; }
    u = S*(1.f/256.f);
    inv = rsqrtf(S2*(1.f/256.f) - u*u + 1e-5f);
    bf16 tmp[32];
#pragma unroll
    for (int i = 0; i < 32; i++) {
        int c = ty*32 + i;
        float xnv = lnw[c]*((vals[i]-u)*inv) + lnb[c];
        xnC[bi + (size_t)i*LPOS] = (bf16)xnv;
        tmp[i] = (bf16)xnv;
    }
    bf16x8* dst = (bf16x8*)&xnT[((size_t)b*LPOS + p)*256 + ty*32];
    bf16x8* srv = (bf16x8*)tmp;
#pragma unroll
    for (int q = 0; q < 4; q++) dst[q] = srv[q];
}

// ---- channel LN over C=256, gated: out = (1-g)*base + g*LN(v); optional pos-major bf16 auxT ----
template<typename Tv, typename Tb, typename To>
__global__ __launch_bounds__(512)
void ln2d_t(const Tv* __restrict__ v, const Tb* __restrict__ base,
            To* __restrict__ out, const float* __restrict__ lnw,
            const float* __restrict__ lnb, const float* __restrict__ gate,
            bf16* __restrict__ auxT)
{
    int b = blockIdx.x >> 6;
    int p = ((blockIdx.x & 63) << 6) + threadIdx.x;
    int ty = threadIdx.y;
    __shared__ float rs[8][64], rs2[8][64];
    float vals[32];
    float s = 0.f, s2 = 0.f;
    size_t bi = ((size_t)b*256 + ty*32)*LPOS + p;
#pragma unroll
    for (int i = 0; i < 32; i++) {
        float x = (float)v[bi + (size_t)i*LPOS];
        vals[i] = x;
        s += x; s2 += x*x;
    }
    rs[ty][threadIdx.x] = s; rs2[ty][threadIdx.x] = s2;
    __syncthreads();
    float S = 0.f, S2 = 0.f;
#pragma unroll
    for (int j = 0; j < 8; j++) { S += rs[j][threadIdx.x]; S2 += rs2[j][threadIdx.x]; }
    float u = S*(1.f/256.f);
    float inv = rsqrtf(S2*(1.f/256.f) - u*u + 1e-5f);
    bf16 tmp[32];
#pragma unroll
    for (int i = 0; i < 32; i++) {
        int c = ty*32 + i;
        float ln = lnw[c]*((vals[i]-u)*inv) + lnb[c];
        float g = sigm(gate[c]);
        float r = (1.f-g)*(float)base[bi + (size_t)i*LPOS] + g*ln;
        out[bi + (size_t)i*LPOS] = (To)r;
        tmp[i] = (bf16)r;
    }
    if (auxT) {
        bf16x8* dst = (bf16x8*)&auxT[((size_t)b*LPOS + p)*256 + ty*32];
        bf16x8* srv = (bf16x8*)tmp;
#pragma unroll
        for (int q = 0; q < 4; q++) dst[q] = srv[q];
    }
}

// ---------------- fp32 -> bf16 convert ----------------
__global__ void f2b_k(const float* __restrict__ in, bf16* __restrict__ out, int n)
{
    int i = blockIdx.x*256 + threadIdx.x;
    if (i < n) out[i] = (bf16)in[i];
}

// ---------------- bcdt_w [192][256] fp32 -> padded [256][256] bf16 (rows>=192 zero) ----------------
__global__ void pad_w_k(const float* __restrict__ w, bf16* __restrict__ out)
{
    int i = blockIdx.x*256 + threadIdx.x;   // 65536
    int r = i >> 8;
    out[i] = (r < 192) ? (bf16)w[(size_t)r*256 + (i & 255)] : (bf16)0.f;
}

// ---------------- Cm [b][64][4096] bf16 -> CmT [b][4096][64] bf16 ----------------
__global__ void transpose_cm_k(const bf16* __restrict__ Cm, bf16* __restrict__ CmT)
{
    int b = blockIdx.y;
    int l0 = blockIdx.x * 64;
    const bf16* src = Cm + (size_t)b * 192 * LPOS;
    bf16* dst = CmT + (size_t)b * LPOS * 64;
    __shared__ float t[64][65];
    int tid = threadIdx.x;
    for (int i = tid; i < 4096; i += 256) {
        int s = i >> 6, l = i & 63;
        t[s][l] = (float)src[(size_t)s*LPOS + l0 + l];
    }
    __syncthreads();
    for (int i = tid; i < 4096; i += 256) {
        int l = i >> 6, s = i & 63;
        dst[(size_t)(l0+l)*64 + s] = (bf16)t[s][l];
    }
}

// ---------------- AB = softmax(dt + A[s]) * Bm -> bf16 ABb [b][64][L] ----------------
__global__ void softmax_ab_k(const bf16* __restrict__ bcdt2, bf16* __restrict__ ABb,
                             const float* __restrict__ Avec)
{
    int b = blockIdx.x >> 6, s = blockIdx.x & 63;
    size_t base = (size_t)b*192*LPOS;
    const bf16* dt = bcdt2 + base + (size_t)(128+s)*LPOS;
    const bf16* Bm = bcdt2 + base + (size_t)s*LPOS;
    bf16* outp = ABb + ((size_t)b*64 + s)*LPOS;
    int tid = threadIdx.x;
    float av = Avec[s];
    float v[16];
    float mx = -1e30f;
#pragma unroll
    for (int i = 0; i < 16; i++) {
        v[i] = (float)dt[tid + (i<<8)] + av;
        mx = fmaxf(mx, v[i]);
    }
    __shared__ float red[256];
    red[tid] = mx; __syncthreads();
    for (int o = 128; o > 0; o >>= 1) {
        if (tid < o) red[tid] = fmaxf(red[tid], red[tid+o]);
        __syncthreads();
    }
    mx = red[0];
    __syncthreads();
    float sum = 0.f;
#pragma unroll
    for (int i = 0; i < 16; i++) { v[i] = expf(v[i]-mx); sum += v[i]; }
    red[tid] = sum; __syncthreads();
    for (int o = 128; o > 0; o >>= 1) {
        if (tid < o) red[tid] += red[tid+o];
        __syncthreads();
    }
    float rinv = 1.f / red[0];
#pragma unroll
    for (int i = 0; i < 16; i++) {
        int idx = tid + (i<<8);
        outp[idx] = (bf16)(v[i] * rinv * (float)Bm[idx]);
    }
}

// ---------------- fused hz -> gate -> ho (bf16 out); one block per batch ----------------
__global__ __launch_bounds__(1024)
void hz_ho_fused_k(const float* __restrict__ h, const float* __restrict__ hz_w,
                   const float* __restrict__ hz_b, const float* __restrict__ outp_w,
                   const float* __restrict__ outp_b, bf16* __restrict__ hob16)
{
    int b = blockIdx.x;
    __shared__ float hld[256*64];     // 64KB
    __shared__ float hgld[256*64];    // 64KB
    const float* hb = h + (size_t)b*16384;
    int tid = threadIdx.x;
    for (int i = tid; i < 16384; i += 1024) hld[i] = hb[i];
    __syncthreads();
    for (int i = tid; i < 16384; i += 1024) {
        int o = i >> 6, s = i & 63;
        float accp = hz_b[o], accz = hz_b[o+256];
        for (int c = 0; c < 256; c++) {
            float hv = hld[c*64 + s];
            accp += hz_w[o*256 + c]*hv;
            accz += hz_w[(o+256)*256 + c]*hv;
        }
        hgld[i] = accp * accz * sigm(accz);
    }
    __syncthreads();
    for (int i = tid; i < 16384; i += 1024) {
        int o = i >> 6, s = i & 63;
        float acc = outp_b[o];
        for (int c = 0; c < 256; c++)
            acc += outp_w[o*256 + c]*hgld[c*64 + s];
        hob16[(size_t)b*16384 + i] = (bf16)acc;
    }
}

// =====================================================================================
// MFMA NT GEMM: D[m][n] = sum_k A[m][k]*B[n][k] (+bias[m]); 128x128 tile, BK=64
// =====================================================================================
template<int OUT_BF16>
__global__ __launch_bounds__(256)
void gemm_nt_mfma(const bf16* __restrict__ A, const bf16* __restrict__ B,
                  void* __restrict__ C, const float* __restrict__ bias, int mlimit,
                  int K, int lda, int ldb, int ldc,
                  size_t abst, size_t bbst, size_t cbst)
{
    int b = blockIdx.z;
    const bf16* Ab = A + (size_t)b*abst;
    const bf16* Bb = B + (size_t)b*bbst;
    int m0 = blockIdx.y*128, n0 = blockIdx.x*128;
    __shared__ bf16 Asl[128*64];
    __shared__ bf16 Bsl[128*64];
    int tid = threadIdx.x;
    int lane = tid & 63;
    int w = tid >> 6;
    int wm = (w >> 1)*64, wn = (w & 1)*64;
    int fm = lane & 15, quad = lane >> 4;
    f32x4 acc[4][4] = {};
    for (int k0 = 0; k0 < K; k0 += 64) {
#pragma unroll
        for (int ii = 0; ii < 4; ii++) {
            int q = ii*256 + tid;
            int row = q >> 3, ko = (q & 7) << 3;
            GLOAD_LDS16(Ab + (size_t)(m0+row)*lda + k0 + ko, &Asl[q*8]);
            GLOAD_LDS16(Bb + (size_t)(n0+row)*ldb + k0 + ko, &Bsl[q*8]);
        }
        __syncthreads();
#pragma unroll
        for (int kk = 0; kk < 2; kk++) {
            bf16x8 af[4], bfr[4];
#pragma unroll
            for (int i = 0; i < 4; i++)
                af[i] = *(const bf16x8*)&Asl[(wm + i*16 + fm)*64 + kk*32 + quad*8];
#pragma unroll
            for (int j = 0; j < 4; j++)
                bfr[j] = *(const bf16x8*)&Bsl[(wn + j*16 + fm)*64 + kk*32 + quad*8];
#pragma unroll
            for (int i = 0; i < 4; i++)
#pragma unroll
                for (int j = 0; j < 4; j++)
                    acc[i][j] = __builtin_amdgcn_mfma_f32_16x16x32_bf16(af[i], bfr[j], acc[i][j], 0, 0, 0);
        }
        __syncthreads();
    }
    size_t cb = (size_t)b*cbst;
#pragma unroll
    for (int i = 0; i < 4; i++) {
#pragma unroll
        for (int r = 0; r < 4; r++) {
            int m = m0 + wm + i*16 + quad*4 + r;
            if (m >= mlimit) continue;
            float bb = bias ? bias[m] : 0.f;
#pragma unroll
            for (int j = 0; j < 4; j++) {
                int n = n0 + wn + j*16 + fm;
                float vv = acc[i][j][r] + bb;
                if (OUT_BF16) ((bf16*)C)[cb + (size_t)m*ldc + n] = (bf16)vv;
                else          ((float*)C)[cb + (size_t)m*ldc + n] = vv;
            }
        }
    }
}

// =====================================================================================
// h-GEMM: h[b][d][s] += sum_l xnC[b][d][l]*ABb[b][s][l]; BM=128, BN=64, split-K atomic
// =====================================================================================
__global__ __launch_bounds__(256)
void gemm_h_mfma(const bf16* __restrict__ xnC, const bf16* __restrict__ ABb,
                 float* __restrict__ h, int Kchunk)
{
    int b = blockIdx.z;
    const bf16* Ab = xnC + (size_t)b*256*LPOS;
    const bf16* Bb = ABb + (size_t)b*64*LPOS;
    float* Cb = h + (size_t)b*256*64;
    int m0 = blockIdx.y*128;
    int kbase = blockIdx.x*Kchunk;
    __shared__ bf16 Asl[128*64];
    __shared__ bf16 Bsl[64*64];
    int tid = threadIdx.x;
    int lane = tid & 63;
    int w = tid >> 6;
    int wm = (w >> 1)*64, wn = (w & 1)*32;
    int fm = lane & 15, quad = lane >> 4;
    f32x4 acc[4][2] = {};
    for (int k0 = kbase; k0 < kbase + Kchunk; k0 += 64) {
#pragma unroll
        for (int ii = 0; ii < 4; ii++) {
            int q = ii*256 + tid;
            int row = q >> 3, ko = (q & 7) << 3;
            GLOAD_LDS16(Ab + (size_t)(m0+row)*LPOS + k0 + ko, &Asl[q*8]);
        }
#pragma unroll
        for (int ii = 0; ii < 2; ii++) {
            int q = ii*256 + tid;
            int row = q >> 3, ko = (q & 7) << 3;
            GLOAD_LDS16(Bb + (size_t)row*LPOS + k0 + ko, &Bsl[q*8]);
        }
        __syncthreads();
#pragma unroll
        for (int kk = 0; kk < 2; kk++) {
            bf16x8 af[4], bfr[2];
#pragma unroll
            for (int i = 0; i < 4; i++)
                af[i] = *(const bf16x8*)&Asl[(wm + i*16 + fm)*64 + kk*32 + quad*8];
#pragma unroll
            for (int j = 0; j < 2; j++)
                bfr[j] = *(const bf16x8*)&Bsl[(wn + j*16 + fm)*64 + kk*32 + quad*8];
#pragma unroll
            for (int i = 0; i < 4; i++)
#pragma unroll
                for (int j = 0; j < 2; j++)
                    acc[i][j] = __builtin_amdgcn_mfma_f32_16x16x32_bf16(af[i], bfr[j], acc[i][j], 0, 0, 0);
        }
        __syncthreads();
    }
#pragma unroll
    for (int i = 0; i < 4; i++)
#pragma unroll
        for (int r = 0; r < 4; r++) {
            int m = m0 + wm + i*16 + quad*4 + r;
#pragma unroll
            for (int j = 0; j < 2; j++) {
                int n = wn + j*16 + fm;
                atomicAdd(&Cb[(size_t)m*64 + n], acc[i][j][r]);
            }
        }
}

// =====================================================================================
// mixer out: x2[b][o][l] = (1-g)*x1 + g*( ho@Cm + xn*Dp ); bf16 in-place on x
// =====================================================================================
__global__ __launch_bounds__(256)
void mixer_out_mfma(const bf16* __restrict__ hoB, const bf16* __restrict__ CmT,
                    const bf16* __restrict__ xnC, bf16* __restrict__ x,
                    const float* __restrict__ Dp, const float* __restrict__ gate)
{
    int b = blockIdx.z;
    const bf16* Ab = hoB + (size_t)b*(256*64);
    const bf16* Bb = CmT + (size_t)b*((size_t)LPOS*64);
    int m0 = blockIdx.y*128, n0 = blockIdx.x*128;
    __shared__ bf16 Asl[128*64];
    __shared__ bf16 Bsl[128*64];
    int tid = threadIdx.x;
    int lane = tid & 63;
    int w = tid >> 6;
    int wm = (w >> 1)*64, wn = (w & 1)*64;
    int fm = lane & 15, quad = lane >> 4;
    f32x4 acc[4][4] = {};
#pragma unroll
    for (int ii = 0; ii < 4; ii++) {
        int q = ii*256 + tid;
        int row = q >> 3, ko = (q & 7) << 3;
        GLOAD_LDS16(Ab + (size_t)(m0+row)*64 + ko, &Asl[q*8]);
        GLOAD_LDS16(Bb + (size_t)(n0+row)*64 + ko, &Bsl[q*8]);
    }
    __syncthreads();
#pragma unroll
    for (int kk = 0; kk < 2; kk++) {
        bf16x8 af[4], bfr[4];
#pragma unroll
        for (int i = 0; i < 4; i++)
            af[i] = *(const bf16x8*)&Asl[(wm + i*16 + fm)*64 + kk*32 + quad*8];
#pragma unroll
        for (int j = 0; j < 4; j++)
            bfr[j] = *(const bf16x8*)&Bsl[(wn + j*16 + fm)*64 + kk*32 + quad*8];
#pragma unroll
        for (int i = 0; i < 4; i++)
#pragma unroll
            for (int j = 0; j < 4; j++)
                acc[i][j] = __builtin_amdgcn_mfma_f32_16x16x32_bf16(af[i], bfr[j], acc[i][j], 0, 0, 0);
    }
#pragma unroll
    for (int i = 0; i < 4; i++) {
#pragma unroll
        for (int r = 0; r < 4; r++) {
            int m = m0 + wm + i*16 + quad*4 + r;
            float g = sigm(gate[m]);
            float dp = Dp[m];
#pragma unroll
            for (int j = 0; j < 4; j++) {
                int n = n0 + wn + j*16 + fm;
                size_t idx = ((size_t)b*256 + m)*LPOS + n;
                float y = acc[i][j][r] + (float)xnC[idx]*dp;
                x[idx] = (bf16)((1.f-g)*(float)x[idx] + g*y);
            }
        }
    }
}

// ---------------- position-major LN + SiLU over C=1024, bf16 in-place ----------------
__global__ void ln_silu_rows_k(bf16* __restrict__ f, const float* __restrict__ w,
                               const float* __restrict__ bvec)
{
    size_t row = (size_t)blockIdx.x*4 + (threadIdx.x >> 6);
    int lane = threadIdx.x & 63;
    bf16* p = f + row*1024 + lane*16;
    bf16x8 v0 = *(const bf16x8*)p;
    bf16x8 v1 = *(const bf16x8*)(p + 8);
    float v[16];
    float s = 0.f, s2 = 0.f;
#pragma unroll
    for (int i = 0; i < 8; i++) { v[i] = (float)v0[i]; v[8+i] = (float)v1[i]; }
#pragma unroll
    for (int i = 0; i < 16; i++) { s += v[i]; s2 += v[i]*v[i]; }
    for (int o = 32; o > 0; o >>= 1) { s += __shfl_xor(s, o); s2 += __shfl_xor(s2, o); }
    float u = s * (1.f/1024.f);
    float inv = rsqrtf(s2 * (1.f/1024.f) - u*u + 1e-5f);
#pragma unroll
    for (int i = 0; i < 16; i++) {
        int c = lane*16 + i;
        float ln = w[c]*((v[i]-u)*inv) + bvec[c];
        v[i] = ln * sigm(ln);
    }
    bf16x8 o0, o1;
#pragma unroll
    for (int i = 0; i < 8; i++) { o0[i] = (bf16)v[i]; o1[i] = (bf16)v[8+i]; }
    *(bf16x8*)p = o0;
    *(bf16x8*)(p + 8) = o1;
}

extern "C" void kernel_launch(void* const* d_in, const int* in_sizes, int n_in,
                              void* d_out, int out_size, void* d_ws, size_t ws_size,
                              hipStream_t stream)
{
    const float* x        = (const float*)d_in[0];
    const float* alpha    = (const float*)d_in[1];
    const float* ln_w     = (const float*)d_in[2];
    const float* ln_b     = (const float*)d_in[3];
    const float* dw1_w    = (const float*)d_in[4];
    const float* dw1_ln_w = (const float*)d_in[5];
    const float* dw1_ln_b = (const float*)d_in[6];
    const float* dw2_w    = (const float*)d_in[7];
    const float* dw2_ln_w = (const float*)d_in[8];
    const float* dw2_ln_b = (const float*)d_in[9];
    const float* bcdt_w   = (const float*)d_in[10];
    const float* bcdt_b   = (const float*)d_in[11];
    const float* dwm_w    = (const float*)d_in[12];
    const float* dwm_b    = (const float*)d_in[13];
    const float* hz_w     = (const float*)d_in[14];
    const float* hz_b     = (const float*)d_in[15];
    const float* outp_w   = (const float*)d_in[16];
    const float* outp_b   = (const float*)d_in[17];
    const float* Avec     = (const float*)d_in[18];
    const float* Dp       = (const float*)d_in[19];
    const float* fc1_w    = (const float*)d_in[20];
    const float* fc1_ln_w = (const float*)d_in[21];
    const float* fc1_ln_b = (const float*)d_in[22];
    const float* fc2_w    = (const float*)d_in[23];
    const float* fc2_ln_w = (const float*)d_in[24];
    const float* fc2_ln_b = (const float*)d_in[25];

    float* outp  = (float*)d_out;
    float* h_out = outp + (size_t)NB*256*LPOS;

    const size_t MB = 1024*1024;
    char* wsb = (char*)d_ws;
    bf16* cb0    = (bf16*)(wsb + 0*MB);      // 32MB: conv1/conv2 out; later f2
    bf16* x1b    = (bf16*)(wsb + 32*MB);     // 32MB: x1 -> x2 -> x3 (in-place)
    bf16* xnC    = (bf16*)(wsb + 64*MB);     // 32MB: channel-major xn; later x3t
    bf16* xnT    = (bf16*)(wsb + 96*MB);     // 32MB: pos-major xn; later f1 part
    bf16* bcdtB  = (bf16*)(wsb + 128*MB);    // 24MB
    bf16* bcdt2B = (bf16*)(wsb + 152*MB);    // 24MB
    bf16* CmT    = (bf16*)(wsb + 176*MB);    // 8MB
    bf16* ABb    = (bf16*)(wsb + 184*MB);    // 8MB
    bf16* x3t    = xnC;                       // reuse after mixer
    bf16* f1buf  = xnT;                       // 128MB span [96,224) (xnT/bcdt/bcdt2/CmT/ABb dead)
    bf16* f2buf  = cb0;                       // 32MB, FFN epilogue
    bf16* hob16  = (bf16*)(wsb + 224*MB);    // 0.5MB
    bf16* wpad   = (bf16*)(wsb + 225*MB);    // 128KB
    bf16* fc1_wb = (bf16*)(wsb + 226*MB);    // 0.5MB
    bf16* fc2_wb = (bf16*)(wsb + 227*MB);    // 0.5MB

    dim3 blk256(256);
    dim3 blkLN(64, 8);

    // weight preps (no deps)
    pad_w_k<<<dim3(256), blk256, 0, stream>>>(bcdt_w, wpad);
    f2b_k<<<dim3(1024), blk256, 0, stream>>>(fc1_w, fc1_wb, 1024*256);
    f2b_k<<<dim3(1024), blk256, 0, stream>>>(fc2_w, fc2_wb, 256*1024);

    // 1. conv1(x) -> cb0 (bf16)
    dwconv3x3_t<float, bf16><<<dim3(NB*256), blk256, 0, stream>>>(x, dw1_w, nullptr, cb0, 256);
    // 2. fused: x1 -> x1b bf16, xn -> xnC + xnT
    ln_x1xn_k<<<dim3(NB*64), blkLN, 0, stream>>>(cb0, x, x1b, xnC, xnT,
                                                 dw1_ln_w, dw1_ln_b, alpha + 0, ln_w, ln_b);
    // 4. bcdt = bcdt_w @ xn + b -> bcdtB (bf16, 192 rows)
    gemm_nt_mfma<1><<<dim3(32, 2, NB), blk256, 0, stream>>>(
        wpad, xnT, (void*)bcdtB, bcdt_b, 192, 256, 256, 256, LPOS,
        0, (size_t)LPOS*256, (size_t)192*LPOS);
    // 5. convm(bcdt) -> bcdt2B
    dwconv3x3_t<bf16, bf16><<<dim3(NB*192), blk256, 0, stream>>>(bcdtB, dwm_w, dwm_b, bcdt2B, 192);
    // 5b. CmT
    transpose_cm_k<<<dim3(64, NB), blk256, 0, stream>>>(bcdt2B + (size_t)64*LPOS, CmT);
    // 6. softmax -> ABb
    softmax_ab_k<<<dim3(NB*64), blk256, 0, stream>>>(bcdt2B, ABb, Avec);
    // 6b. zero h
    hipMemsetAsync(h_out, 0, (size_t)NB*256*64*sizeof(float), stream);
    // 7. h = xn . AB^T
    gemm_h_mfma<<<dim3(4, 2, NB), blk256, 0, stream>>>(xnC, ABb, h_out, 1024);
    // 8-10. fused hz -> gate -> ho (bf16)
    hz_ho_fused_k<<<dim3(NB), dim3(1024), 0, stream>>>(h_out, hz_w, hz_b, outp_w, outp_b, hob16);
    // 11. x2 = (1-a1)x1 + a1*(ho@Cm + xn*Dp), in-place on x1b
    mixer_out_mfma<<<dim3(32, 2, NB), blk256, 0, stream>>>(hob16, CmT, xnC, x1b, Dp, alpha + 256);
    // 12. conv2(x2) -> cb0
    dwconv3x3_t<bf16, bf16><<<dim3(NB*256), blk256, 0, stream>>>(x1b, dw2_w, nullptr, cb0, 256);
    // 13. x3 = (1-a2)x2 + a2*LN(conv2), in-place x1b, + x3t pos-major
    ln2d_t<bf16, bf16, bf16><<<dim3(NB*64), blkLN, 0, stream>>>(
        cb0, x1b, x1b, dw2_ln_w, dw2_ln_b, alpha + 512, x3t);
    // 14. FFN, single pass over all 16 batches
    gemm_nt_mfma<1><<<dim3(8, 32, NB), blk256, 0, stream>>>(
        x3t, fc1_wb, (void*)f1buf, nullptr, 1<<30, 256, 256, 256, 1024,
        (size_t)LPOS*256, 0, (size_t)LPOS*1024);
    ln_silu_rows_k<<<dim3(NB*LPOS/4), blk256, 0, stream>>>(f1buf, fc1_ln_w, fc1_ln_b);
    gemm_nt_mfma<1><<<dim3(32, 2, NB), blk256, 0, stream>>>(
        fc2_wb, f1buf, (void*)f2buf, nullptr, 1<<30, 1024, 1024, 1024, LPOS,
        0, (size_t)LPOS*1024, (size_t)256*LPOS);
    ln2d_t<bf16, bf16, float><<<dim3(NB*64), blkLN, 0, stream>>>(
        f2buf, x1b, outp, fc2_ln_w, fc2_ln_b, alpha + 768, nullptr);
}